// Round 1
// baseline (96.757 us; speedup 1.0000x reference)
//
#include <hip/hip_runtime.h>
#include <math.h>

#define BS   8192
#define NCTX 28
#define DM   28
#define IPB  8            // items per block
#define TPI  32           // threads per item (28 active)
#define BLOCK (IPB*TPI)   // 256

__global__ __launch_bounds__(BLOCK) void l1att_fused(
    const float* __restrict__ x,
    const float* __restrict__ Wq, const float* __restrict__ bq,
    const float* __restrict__ Wk, const float* __restrict__ bk,
    const float* __restrict__ Wv, const float* __restrict__ bv,
    const float* __restrict__ W1, const float* __restrict__ b1,
    const float* __restrict__ W2, const float* __restrict__ b2,
    float* __restrict__ out)
{
    // q row-major (broadcast reads), v transposed (stride-1 lane access)
    __shared__ float q_lds[IPB][NCTX*DM];    // 8*784*4 = 25088 B
    __shared__ float vT_lds[IPB][DM*NCTX];   // 25088 B
    __shared__ float l1_lds[IPB][NCTX];
    __shared__ float h_lds[IPB][20];

    const int t    = threadIdx.x;
    const int item = t >> 5;      // 0..7
    const int m    = t & 31;      // row, 0..27 active
    const int b    = blockIdx.x * IPB + item;

    float xr[DM];
    float kr[DM];

    const bool active = (m < NCTX);

    if (active) {
        // ---- load x row (7x float4, contiguous per thread) ----
        const float4* xp = (const float4*)(x + ((size_t)b * NCTX + m) * DM);
        #pragma unroll
        for (int i = 0; i < DM/4; ++i) {
            float4 v4 = xp[i];
            xr[4*i+0] = v4.x; xr[4*i+1] = v4.y; xr[4*i+2] = v4.z; xr[4*i+3] = v4.w;
        }
        // ---- k row: FULLY unrolled so kr[] has only static indices (stays in VGPRs) ----
        #pragma unroll
        for (int c = 0; c < DM; ++c) {
            float ak = bk[c];                // uniform -> scalar load
            #pragma unroll
            for (int w = 0; w < DM; ++w) ak += xr[w] * Wk[c*DM + w];  // s_load weights
            kr[c] = ak;
        }
        // ---- q, v rows: runtime c loop, results to LDS (no reg indexing) ----
        for (int c = 0; c < DM; ++c) {
            float aq = bq[c];
            float av = bv[c];
            #pragma unroll
            for (int w = 0; w < DM; ++w) {
                aq += xr[w] * Wq[c*DM + w];
                av += xr[w] * Wv[c*DM + w];
            }
            q_lds[item][m*DM + c]   = aq;    // stride-28 write, ~4-way, only 28 of them
            vT_lds[item][c*NCTX + m] = av;   // lane-stride-1: conflict-free
        }
    }
    __syncthreads();

    // ---- L1 attention + row-dot with v ----
    if (active) {
        const float* qb = q_lds[item];
        const float* vb = vT_lds[item];
        float acc = 0.f;
        for (int j = 0; j < NCTX; ++j) {
            const float4* qj = (const float4*)(qb + j*DM);  // j*112 B, 16B-aligned
            float s0 = 0.f, s1 = 0.f, s2 = 0.f, s3 = 0.f;
            #pragma unroll
            for (int w4 = 0; w4 < DM/4; ++w4) {
                float4 qv = qj[w4];          // wave-uniform per item -> LDS broadcast
                s0 += fabsf(qv.x - kr[4*w4+0]);
                s1 += fabsf(qv.y - kr[4*w4+1]);
                s2 += fabsf(qv.z - kr[4*w4+2]);
                s3 += fabsf(qv.w - kr[4*w4+3]);
            }
            float s = (s0 + s1) + (s2 + s3);
            const float scale = -0.18898223650461363f;   // -1/sqrt(28)
            float a = (j == m) ? 1.0f : scale * s;       // diagonal override
            acc += vb[j*NCTX + m] * a;                   // v[b,m,j], stride-1 lanes
        }
        l1_lds[item][m] = acc;
    }
    __syncthreads();

    // ---- MLP layer 1: (28)->(20), relu ----
    if (m < 20) {
        float a = b1[m];
        #pragma unroll
        for (int w = 0; w < NCTX; ++w) a += l1_lds[item][w] * W1[m*NCTX + w];
        h_lds[item][m] = fmaxf(a, 0.f);
    }
    __syncthreads();

    // ---- MLP layer 2: (20)->(10) ----
    if (m < 10) {
        float a = b2[m];
        #pragma unroll
        for (int w = 0; w < 20; ++w) a += h_lds[item][w] * W2[m*20 + w];
        out[(size_t)b*10 + m] = a;
    }
}

extern "C" void kernel_launch(void* const* d_in, const int* in_sizes, int n_in,
                              void* d_out, int out_size, void* d_ws, size_t ws_size,
                              hipStream_t stream) {
    const float* x  = (const float*)d_in[0];
    const float* Wq = (const float*)d_in[1];
    const float* bq = (const float*)d_in[2];
    const float* Wk = (const float*)d_in[3];
    const float* bk = (const float*)d_in[4];
    const float* Wv = (const float*)d_in[5];
    const float* bv = (const float*)d_in[6];
    const float* W1 = (const float*)d_in[7];
    const float* b1 = (const float*)d_in[8];
    const float* W2 = (const float*)d_in[9];
    const float* b2 = (const float*)d_in[10];
    float* out = (float*)d_out;

    dim3 grid(BS / IPB), block(BLOCK);
    hipLaunchKernelGGL(l1att_fused, grid, block, 0, stream,
                       x, Wq, bq, Wk, bk, Wv, bv, W1, b1, W2, b2, out);
}

// Round 2
// 65.656 us; speedup vs baseline: 1.4737x; 1.4737x over previous
//
#include <hip/hip_runtime.h>
#include <math.h>

#define BS    8192
#define NCTX  28
#define DM    28
#define IPB   4
#define TPI   32
#define BLOCK (IPB*TPI)     // 128 threads, 2 waves
#define XSTRIDE 29          // padded x row stride (floats); odd -> conflict-free b32
#define QSTRIDE 28          // q row stride: 112 B, 16B-aligned for b128 reads

__global__ __launch_bounds__(BLOCK, 4) void l1att_fused(
    const float* __restrict__ x,
    const float* __restrict__ Wq, const float* __restrict__ bq,
    const float* __restrict__ Wk, const float* __restrict__ bk,
    const float* __restrict__ Wv, const float* __restrict__ bv,
    const float* __restrict__ W1, const float* __restrict__ b1,
    const float* __restrict__ W2, const float* __restrict__ b2,
    float* __restrict__ out)
{
    // x rows live here first (stride 29); after a barrier, q rows (stride 28)
    // overwrite the same storage. 4*812*4 = 12992 B.
    __shared__ float scratch[IPB][NCTX*XSTRIDE];
    __shared__ float l1_lds[IPB][NCTX];   // 448 B
    __shared__ float h_lds[IPB][20];      // 320 B   -> total ~13.8 KB/block

    const int t    = threadIdx.x;
    const int item = t >> 5;      // 0..3
    const int m    = t & 31;      // row, 0..27 active
    const int b    = blockIdx.x * IPB + item;
    const bool active = (m < NCTX);

    float qr[DM], kr[DM], vr[DM];

    if (active) {
        // ---- stage own x row into padded LDS (coalesced-ish float4 global loads) ----
        const float4* xp = (const float4*)(x + ((size_t)b * NCTX + m) * DM);
        float xt[DM];
        #pragma unroll
        for (int i = 0; i < DM/4; ++i) {
            float4 v4 = xp[i];
            xt[4*i+0]=v4.x; xt[4*i+1]=v4.y; xt[4*i+2]=v4.z; xt[4*i+3]=v4.w;
        }
        #pragma unroll
        for (int w = 0; w < DM; ++w) scratch[item][m*XSTRIDE + w] = xt[w];

        // ---- init accumulators with biases (uniform -> s_load) ----
        #pragma unroll
        for (int c = 0; c < DM; ++c) { qr[c] = bq[c]; kr[c] = bk[c]; vr[c] = bv[c]; }

        // ---- qkv: runtime-w loop, 84 static register accumulators ----
        const float* xrow = &scratch[item][m*XSTRIDE];
        #pragma unroll 1
        for (int w = 0; w < DM; ++w) {
            float xw = xrow[w];              // own row, conflict-free (odd stride)
            #pragma unroll
            for (int c = 0; c < DM; ++c) {
                qr[c] = fmaf(xw, Wq[c*DM + w], qr[c]);   // weights: uniform s_loads
                kr[c] = fmaf(xw, Wk[c*DM + w], kr[c]);
                vr[c] = fmaf(xw, Wv[c*DM + w], vr[c]);
            }
        }
    }
    __syncthreads();   // all lanes done reading x before q overwrites scratch

    if (active) {
        // ---- publish q row (7x ds_write_b128, 16B-aligned) ----
        float4* qdst = (float4*)(&scratch[item][m*QSTRIDE]);
        #pragma unroll
        for (int i = 0; i < DM/4; ++i)
            qdst[i] = make_float4(qr[4*i+0], qr[4*i+1], qr[4*i+2], qr[4*i+3]);
    }
    __syncthreads();

    if (active) {
        // ---- L1 attention + row-dot with v (k, v register-resident) ----
        const float scale = -0.18898223650461363f;   // -1/sqrt(28)
        const float* qbase = &scratch[item][0];
        float acc = 0.f;
        #pragma unroll
        for (int j = 0; j < NCTX; ++j) {
            const float4* qj = (const float4*)(qbase + j*QSTRIDE);  // broadcast read
            float s0 = 0.f, s1 = 0.f, s2 = 0.f, s3 = 0.f;
            #pragma unroll
            for (int w4 = 0; w4 < DM/4; ++w4) {
                float4 qv = qj[w4];
                s0 += fabsf(qv.x - kr[4*w4+0]);
                s1 += fabsf(qv.y - kr[4*w4+1]);
                s2 += fabsf(qv.z - kr[4*w4+2]);
                s3 += fabsf(qv.w - kr[4*w4+3]);
            }
            float a = (j == m) ? 1.0f : scale * ((s0 + s1) + (s2 + s3));
            acc = fmaf(vr[j], a, acc);
        }
        l1_lds[item][m] = acc;
    }
    __syncthreads();

    // ---- MLP layer 1: 28 -> 20, relu ----
    if (m < 20) {
        float a = b1[m];
        #pragma unroll
        for (int w = 0; w < NCTX; ++w) a += l1_lds[item][w] * W1[m*NCTX + w];
        h_lds[item][m] = fmaxf(a, 0.f);
    }
    __syncthreads();

    // ---- MLP layer 2: 20 -> 10 ----
    if (m < 10) {
        float a = b2[m];
        #pragma unroll
        for (int w = 0; w < 20; ++w) a += h_lds[item][w] * W2[m*20 + w];
        out[(size_t)b*10 + m] = a;
    }
}

extern "C" void kernel_launch(void* const* d_in, const int* in_sizes, int n_in,
                              void* d_out, int out_size, void* d_ws, size_t ws_size,
                              hipStream_t stream) {
    const float* x  = (const float*)d_in[0];
    const float* Wq = (const float*)d_in[1];
    const float* bq = (const float*)d_in[2];
    const float* Wk = (const float*)d_in[3];
    const float* bk = (const float*)d_in[4];
    const float* Wv = (const float*)d_in[5];
    const float* bv = (const float*)d_in[6];
    const float* W1 = (const float*)d_in[7];
    const float* b1 = (const float*)d_in[8];
    const float* W2 = (const float*)d_in[9];
    const float* b2 = (const float*)d_in[10];
    float* out = (float*)d_out;

    dim3 grid(BS / IPB), block(BLOCK);
    hipLaunchKernelGGL(l1att_fused, grid, block, 0, stream,
                       x, Wq, bq, Wk, bk, Wv, bv, W1, b1, W2, b2, out);
}